// Round 1
// baseline (142.590 us; speedup 1.0000x reference)
//
#include <hip/hip_runtime.h>

// ---------------------------------------------------------------------------
// Key insight: the output depends ONLY on positions[0:64]. winner[] indices
// are in [0,64), so feat[] is only read for the first 64 rows. The 500k-row
// MLP in the reference is dead code. Total real work ~25 MFLOP.
// ---------------------------------------------------------------------------

#define GP 64   // grid points / pos rows used

// K1 (1 block, 256 thr): idx/winner, h1 = relu(pos@W1+b1) (64x64),
// h2 = relu(h1@W2+b2) (64x128) -> ws. winner -> ws.
__global__ __launch_bounds__(256) void k1_backbone(
    const float* __restrict__ positions,   // (N,3) -- only first 64 rows used
    const float* __restrict__ grid,        // (64,3)
    const float* __restrict__ W1, const float* __restrict__ b1,   // (3,64),(64)
    const float* __restrict__ W2, const float* __restrict__ b2,   // (64,128),(128)
    float* __restrict__ h2_ws,             // out: (64,128)
    int* __restrict__ winner_ws)           // out: (64)
{
    __shared__ float pos_s[192];
    __shared__ float grid_s[192];
    __shared__ int   idx_s[GP];
    __shared__ int   win_s[GP];
    __shared__ float h1_s[GP][64];

    const int tid = threadIdx.x;
    if (tid < 192) { pos_s[tid] = positions[tid]; grid_s[tid] = grid[tid]; }
    __syncthreads();

    // nearest grid point per position (first-min tie-break == jnp.argmin)
    if (tid < GP) {
        const float px = pos_s[tid*3], py = pos_s[tid*3+1], pz = pos_s[tid*3+2];
        float best = 3.4e38f; int bi = 0;
        for (int g = 0; g < GP; ++g) {
            const float dx = px - grid_s[g*3];
            const float dy = py - grid_s[g*3+1];
            const float dz = pz - grid_s[g*3+2];
            const float d2 = dx*dx + dy*dy + dz*dz;
            if (d2 < best) { best = d2; bi = g; }
        }
        idx_s[tid] = bi;
    }
    __syncthreads();
    // winner[g] = max{ i : idx[i]==g } else -1.  i ascending => plain overwrite.
    if (tid == 0) {
        for (int g = 0; g < GP; ++g) win_s[g] = -1;
        for (int i = 0; i < GP; ++i) win_s[idx_s[i]] = i;
    }
    __syncthreads();
    if (tid < GP) winner_ws[tid] = win_s[tid];

    // h1 = relu(pos @ W1 + b1): 64x64, 16 rows/thread
    {
        const int j  = tid & 63;
        const int i0 = tid >> 6;             // 0..3
        const float w0 = W1[0*64 + j], w1 = W1[1*64 + j], w2 = W1[2*64 + j];
        const float bb = b1[j];
        #pragma unroll
        for (int m = 0; m < 16; ++m) {
            const int i = i0 + 4*m;
            const float acc = bb + pos_s[i*3]*w0 + pos_s[i*3+1]*w1 + pos_s[i*3+2]*w2;
            h1_s[i][j] = fmaxf(acc, 0.f);
        }
    }
    __syncthreads();

    // h2 = relu(h1 @ W2 + b2): 64x128 -> global ws; 32 independent accs/thread
    {
        const int j  = tid & 127;
        const int i0 = tid >> 7;             // 0..1
        float acc[32];
        const float bb = b2[j];
        #pragma unroll
        for (int m = 0; m < 32; ++m) acc[m] = bb;
        for (int k = 0; k < 64; k += 4) {
            const float w0 = W2[(k+0)*128 + j];
            const float w1 = W2[(k+1)*128 + j];
            const float w2 = W2[(k+2)*128 + j];
            const float w3 = W2[(k+3)*128 + j];
            #pragma unroll
            for (int m = 0; m < 32; ++m) {
                const int i = i0 + 2*m;
                const float4 h4 = *(const float4*)&h1_s[i][k];  // wave-broadcast
                acc[m] += h4.x*w0 + h4.y*w1 + h4.z*w2 + h4.w*w3;
            }
        }
        #pragma unroll
        for (int m = 0; m < 32; ++m) {
            const int i = i0 + 2*m;
            h2_ws[i*128 + j] = fmaxf(acc[m], 0.f);
        }
    }
}

// K2 (8 blocks, 256 thr): block b handles grid rows [8b,8b+8):
//   gf[g][j] = winner>=0 ? b3[j] + h2[winner[g]] . W3[:,j] : 0
//   partial[j] = sum_g relu(bn1[j] + gf[g][:] . Wn1[:,j])   -> tbar_part[b]
__global__ __launch_bounds__(256) void k2_grid(
    const float* __restrict__ W3, const float* __restrict__ b3,    // (128,256),(256)
    const float* __restrict__ Wn1, const float* __restrict__ bn1,  // (256,256),(256)
    const float* __restrict__ h2_ws,                                // (64,128)
    const int* __restrict__ winner_ws,                              // (64)
    float* __restrict__ tbar_part)                                  // (8,256)
{
    __shared__ float h2r_s[8][128];
    __shared__ float gf_s[8][256];
    __shared__ int   win_s[8];

    const int tid = threadIdx.x;
    const int b   = blockIdx.x;
    const int g0  = b * 8;

    if (tid < 8) win_s[tid] = winner_ws[g0 + tid];
    __syncthreads();

    // stage gathered h2 rows (zeros where no winner)
    #pragma unroll
    for (int t = 0; t < 4; ++t) {
        const int e  = tid + t*256;
        const int gl = e >> 7;        // 0..7
        const int d  = e & 127;
        const int r  = win_s[gl];
        h2r_s[gl][d] = (r >= 0) ? h2_ws[r*128 + d] : 0.f;
    }
    __syncthreads();

    // gf rows for this block
    {
        const int j = tid;
        float acc[8];
        #pragma unroll
        for (int g = 0; g < 8; ++g) acc[g] = 0.f;
        for (int d = 0; d < 128; d += 4) {
            const float w0 = W3[(d+0)*256 + j];
            const float w1 = W3[(d+1)*256 + j];
            const float w2 = W3[(d+2)*256 + j];
            const float w3 = W3[(d+3)*256 + j];
            #pragma unroll
            for (int g = 0; g < 8; ++g) {
                const float4 h4 = *(const float4*)&h2r_s[g][d];  // wave-broadcast
                acc[g] += h4.x*w0 + h4.y*w1 + h4.z*w2 + h4.w*w3;
            }
        }
        const float bb = b3[j];
        #pragma unroll
        for (int g = 0; g < 8; ++g)
            gf_s[g][j] = (win_s[g] >= 0) ? (acc[g] + bb) : 0.f;
    }
    __syncthreads();

    // t = relu(gf @ Wn1 + bn1), summed over this block's 8 rows
    {
        const int j = tid;
        float acc[8];
        const float bb = bn1[j];
        #pragma unroll
        for (int g = 0; g < 8; ++g) acc[g] = bb;
        for (int c = 0; c < 256; c += 4) {
            const float w0 = Wn1[(c+0)*256 + j];
            const float w1 = Wn1[(c+1)*256 + j];
            const float w2 = Wn1[(c+2)*256 + j];
            const float w3 = Wn1[(c+3)*256 + j];
            #pragma unroll
            for (int g = 0; g < 8; ++g) {
                const float4 g4 = *(const float4*)&gf_s[g][c];   // wave-broadcast
                acc[g] += g4.x*w0 + g4.y*w1 + g4.z*w2 + g4.w*w3;
            }
        }
        float psum = 0.f;
        #pragma unroll
        for (int g = 0; g < 8; ++g) psum += fmaxf(acc[g], 0.f);
        tbar_part[b*256 + j] = psum;
    }
}

// K3 (1 block, 256 thr): tbar -> agg = tbar@Wn2+bn2 -> heads -> out[4]
__global__ __launch_bounds__(256) void k3_head(
    const float* __restrict__ Wn2, const float* __restrict__ bn2,  // (256,256),(256)
    const float* __restrict__ Wh1, const float* __restrict__ bh1,  // (4,256,128),(4,128)
    const float* __restrict__ Wh2, const float* __restrict__ bh2,  // (4,128,1),(4,1)
    const float* __restrict__ tbar_part,                            // (8,256)
    float* __restrict__ out)                                        // (4)
{
    __shared__ float tbar_s[256];
    __shared__ float agg_s[256];
    __shared__ float h1h_s[4][128];

    const int tid = threadIdx.x;

    // mean over the 64 grid rows, assembled from the 8 block-partials
    float tb = 0.f;
    #pragma unroll
    for (int b = 0; b < 8; ++b) tb += tbar_part[b*256 + tid];
    tbar_s[tid] = tb * (1.f/64.f);
    __syncthreads();

    // agg[c] = bn2[c] + sum_j tbar[j]*Wn2[j][c]
    {
        const int c = tid;
        float acc = bn2[c];
        for (int j = 0; j < 256; j += 4) {
            const float4 t4 = *(const float4*)&tbar_s[j];        // wave-broadcast
            acc += t4.x * Wn2[(j+0)*256 + c] + t4.y * Wn2[(j+1)*256 + c]
                 + t4.z * Wn2[(j+2)*256 + c] + t4.w * Wn2[(j+3)*256 + c];
        }
        agg_s[c] = acc;
    }
    __syncthreads();

    // heads: h1h[k][d] = relu(bh1[k][d] + sum_c agg[c]*Wh1[k][c][d]); 512 elems
    #pragma unroll
    for (int t = 0; t < 2; ++t) {
        const int e = tid + t*256;
        const int k = e >> 7;
        const int d = e & 127;
        float acc = bh1[k*128 + d];
        for (int c = 0; c < 256; c += 4) {
            const float4 a4 = *(const float4*)&agg_s[c];         // wave-broadcast
            const float* wp = &Wh1[(k*256 + c)*128 + d];
            acc += a4.x * wp[0] + a4.y * wp[128] + a4.z * wp[256] + a4.w * wp[384];
        }
        h1h_s[k][d] = fmaxf(acc, 0.f);
    }
    __syncthreads();

    if (tid < 4) {
        float acc = bh2[tid];
        for (int d = 0; d < 128; ++d) acc += h1h_s[tid][d] * Wh2[tid*128 + d];
        out[tid] = acc;
    }
}

extern "C" void kernel_launch(void* const* d_in, const int* in_sizes, int n_in,
                              void* d_out, int out_size, void* d_ws, size_t ws_size,
                              hipStream_t stream) {
    const float* positions = (const float*)d_in[0];
    const float* grid      = (const float*)d_in[1];
    const float* W1  = (const float*)d_in[2];
    const float* b1  = (const float*)d_in[3];
    const float* W2  = (const float*)d_in[4];
    const float* b2  = (const float*)d_in[5];
    const float* W3  = (const float*)d_in[6];
    const float* b3  = (const float*)d_in[7];
    const float* Wn1 = (const float*)d_in[8];
    const float* bn1 = (const float*)d_in[9];
    const float* Wn2 = (const float*)d_in[10];
    const float* bn2 = (const float*)d_in[11];
    const float* Wh1 = (const float*)d_in[12];
    const float* bh1 = (const float*)d_in[13];
    const float* Wh2 = (const float*)d_in[14];
    const float* bh2 = (const float*)d_in[15];
    float* out = (float*)d_out;

    // workspace layout (fully rewritten every call; poison-safe)
    char* ws = (char*)d_ws;
    float* h2_ws     = (float*)ws;                         // 64*128 f32 = 32 KB
    int*   winner_ws = (int*)(ws + 64*128*4);              // 64 i32
    float* tbar_part = (float*)(ws + 64*128*4 + 64*4);     // 8*256 f32

    hipLaunchKernelGGL(k1_backbone, dim3(1), dim3(256), 0, stream,
                       positions, grid, W1, b1, W2, b2, h2_ws, winner_ws);
    hipLaunchKernelGGL(k2_grid, dim3(8), dim3(256), 0, stream,
                       W3, b3, Wn1, bn1, h2_ws, winner_ws, tbar_part);
    hipLaunchKernelGGL(k3_head, dim3(1), dim3(256), 0, stream,
                       Wn2, bn2, Wh1, bh1, Wh2, bh2, tbar_part, out);
}

// Round 3
// 135.155 us; speedup vs baseline: 1.0550x; 1.0550x over previous
//
#include <hip/hip_runtime.h>

// ---------------------------------------------------------------------------
// Output depends ONLY on positions[0:64] (winner indices are in [0,64), feat
// is only read at feat[winner]). The 500k-row MLP is dead code. ~25 MFLOP.
//
// R2: two kernels (the single cross-block dependency tpart->tbar is carried
// by the inter-kernel stream barrier -- no atomics/fences, XCD-coherence-safe).
//  - A (8 blocks x 256): winner calc, h1/h2 ONLY for this block's 8 winner
//    rows, gf (8x256), Wn1-stage partial tbar -> ws. Chunked 16/32-wide
//    independent register preloads of weights (latency hiding). Ends by
//    warming this block's 1/8 of Wn2/Wh1 into L2/L3 for kernel B.
//  - B (1 block x 256): tbar -> agg -> heads -> out. Final Wh2 dot kept as
//    the R0-proven strictly-sequential scalar loop (bit-exact at bf16).
// All accumulation orders are identical to the R0 kernel that scored
// absmax 0.0 -- do not regroup any reduction.
// ---------------------------------------------------------------------------

__global__ __launch_bounds__(256) void kA_grid(
    const float* __restrict__ positions, const float* __restrict__ grid,
    const float* __restrict__ W1, const float* __restrict__ b1,
    const float* __restrict__ W2, const float* __restrict__ b2,
    const float* __restrict__ W3, const float* __restrict__ b3,
    const float* __restrict__ Wn1, const float* __restrict__ bn1,
    const float* __restrict__ Wn2, const float* __restrict__ Wh1,
    float* __restrict__ tpart_ws,     // (8,256)
    float* __restrict__ warm_ws)      // (8,256) dummy sink for L3-warm loads
{
    __shared__ float pos_s[192], grid_s[192], w1_s[192], b1_s[64];
    __shared__ int   idx_s[64];
    __shared__ int   win_s[8];
    __shared__ __align__(16) float h1_s[8][64];
    __shared__ __align__(16) float h2_s[8][128];
    __shared__ __align__(16) float gf_s[8][256];

    const int tid = threadIdx.x;
    const int b   = blockIdx.x;

    if (tid < 192) { pos_s[tid] = positions[tid]; grid_s[tid] = grid[tid]; w1_s[tid] = W1[tid]; }
    if (tid >= 192) b1_s[tid - 192] = b1[tid - 192];
    __syncthreads();

    // nearest grid point per position (first-min tie-break == jnp.argmin)
    if (tid < 64) {
        const float px = pos_s[tid*3], py = pos_s[tid*3+1], pz = pos_s[tid*3+2];
        float best = 3.4e38f; int bi = 0;
        for (int g = 0; g < 64; ++g) {
            const float dx = px - grid_s[g*3];
            const float dy = py - grid_s[g*3+1];
            const float dz = pz - grid_s[g*3+2];
            const float d2 = dx*dx + dy*dy + dz*dz;
            if (d2 < best) { best = d2; bi = g; }
        }
        idx_s[tid] = bi;
    }
    __syncthreads();

    // this block's 8 winners: winner[g] = max{i : idx[i]==g} else -1
    if (tid < 8) {
        const int g = b*8 + tid;
        int m = -1;
        for (int i = 0; i < 64; ++i) if (idx_s[i] == g) m = i;
        win_s[tid] = m;
    }
    __syncthreads();

    // h1 for the 8 winner rows only (row = clip(winner,0), matches reference)
    #pragma unroll
    for (int u = 0; u < 2; ++u) {
        const int e = tid + u*256;
        const int t = e >> 6, k = e & 63;
        int r = win_s[t]; if (r < 0) r = 0;
        const float acc = b1_s[k] + pos_s[r*3]*w1_s[k] + pos_s[r*3+1]*w1_s[64+k]
                                  + pos_s[r*3+2]*w1_s[128+k];
        h1_s[t][k] = fmaxf(acc, 0.f);
    }
    __syncthreads();

    // h2 (8x128): thread d=tid&127 handles slots {t0, t0+2, t0+4, t0+6}
    {
        const int d = tid & 127, t0 = tid >> 7;
        float acc[4];
        const float bb = b2[d];
        #pragma unroll
        for (int m = 0; m < 4; ++m) acc[m] = bb;
        for (int kc = 0; kc < 64; kc += 16) {
            float w[16];
            #pragma unroll
            for (int u = 0; u < 16; ++u) w[u] = W2[(kc+u)*128 + d];   // 16 indep loads
            #pragma unroll
            for (int u = 0; u < 16; u += 4) {
                #pragma unroll
                for (int m = 0; m < 4; ++m) {
                    const float4 h4 = *(const float4*)&h1_s[t0 + 2*m][kc + u];
                    acc[m] += h4.x*w[u] + h4.y*w[u+1] + h4.z*w[u+2] + h4.w*w[u+3];
                }
            }
        }
        #pragma unroll
        for (int m = 0; m < 4; ++m) h2_s[t0 + 2*m][d] = fmaxf(acc[m], 0.f);
    }
    __syncthreads();

    // gf (8x256): thread j; 128-deep dot against W3 columns
    {
        const int j = tid;
        float acc[8];
        #pragma unroll
        for (int t = 0; t < 8; ++t) acc[t] = 0.f;
        for (int dc = 0; dc < 128; dc += 16) {
            float w[16];
            #pragma unroll
            for (int u = 0; u < 16; ++u) w[u] = W3[(dc+u)*256 + j];   // 16 indep loads
            #pragma unroll
            for (int u = 0; u < 16; u += 4) {
                #pragma unroll
                for (int t = 0; t < 8; ++t) {
                    const float4 h4 = *(const float4*)&h2_s[t][dc + u];
                    acc[t] += h4.x*w[u] + h4.y*w[u+1] + h4.z*w[u+2] + h4.w*w[u+3];
                }
            }
        }
        const float bb = b3[j];
        #pragma unroll
        for (int t = 0; t < 8; ++t)
            gf_s[t][j] = (win_s[t] >= 0) ? (acc[t] + bb) : 0.f;
    }
    __syncthreads();

    // Wn1 stage: tpart[j] = sum_t relu(bn1[j] + gf[t][:] . Wn1[:,j])
    {
        const int j = tid;
        float acc[8];
        const float bb = bn1[j];
        #pragma unroll
        for (int t = 0; t < 8; ++t) acc[t] = bb;
        for (int cc = 0; cc < 256; cc += 32) {
            float w[32];
            #pragma unroll
            for (int u = 0; u < 32; ++u) w[u] = Wn1[(cc+u)*256 + j];  // 32 indep loads
            #pragma unroll
            for (int u = 0; u < 32; u += 4) {
                #pragma unroll
                for (int t = 0; t < 8; ++t) {
                    const float4 g4 = *(const float4*)&gf_s[t][cc + u];
                    acc[t] += g4.x*w[u] + g4.y*w[u+1] + g4.z*w[u+2] + g4.w*w[u+3];
                }
            }
        }
        float ps = 0.f;
        #pragma unroll
        for (int t = 0; t < 8; ++t) ps += fmaxf(acc[t], 0.f);
        tpart_ws[b*256 + tid] = ps;
    }

    // warm this block's 1/8 slice of Wn2 + Wh1 into L2/L3 for kernel B
    // (sink store forces the loads; *0.0f not foldable without fast-math)
    {
        float s = 0.f;
        const float* wn2p = Wn2 + b*8192;
        #pragma unroll 8
        for (int u = 0; u < 32; ++u) s += wn2p[tid + u*256];
        const float* wh1p = Wh1 + b*16384;
        #pragma unroll 8
        for (int u = 0; u < 64; ++u) s += wh1p[tid + u*256];
        warm_ws[b*256 + tid] = s * 0.0f;
    }
}

__global__ __launch_bounds__(256) void kB_head(
    const float* __restrict__ Wn2, const float* __restrict__ bn2,
    const float* __restrict__ Wh1, const float* __restrict__ bh1,
    const float* __restrict__ Wh2, const float* __restrict__ bh2,
    const float* __restrict__ tpart_ws,                             // (8,256)
    float* __restrict__ out)                                        // (4)
{
    __shared__ __align__(16) float tbar_s[256];
    __shared__ __align__(16) float agg_s[256];
    __shared__ __align__(16) float h1h_s[4][128];

    const int tid = threadIdx.x;

    // mean over the 64 grid rows, assembled from the 8 block-partials
    {
        float tb = 0.f;
        #pragma unroll
        for (int q = 0; q < 8; ++q) tb += tpart_ws[q*256 + tid];
        tbar_s[tid] = tb * (1.f/64.f);
    }
    __syncthreads();

    {   // agg[c] = bn2[c] + tbar . Wn2[:,c]
        const int c = tid;
        float acc = bn2[c];
        for (int jc = 0; jc < 256; jc += 32) {
            float w[32];
            #pragma unroll
            for (int u = 0; u < 32; ++u) w[u] = Wn2[(jc+u)*256 + c];  // L3-warm
            #pragma unroll
            for (int u = 0; u < 32; u += 4) {
                const float4 t4 = *(const float4*)&tbar_s[jc + u];
                acc += t4.x*w[u] + t4.y*w[u+1] + t4.z*w[u+2] + t4.w*w[u+3];
            }
        }
        agg_s[c] = acc;
    }
    __syncthreads();

    {   // heads: 512 outputs, 2 per thread, loads for both interleaved
        const int k0 = tid >> 7, d0 = tid & 127;
        const int e1 = tid + 256;
        const int k1 = e1 >> 7, d1 = e1 & 127;
        float a0 = bh1[k0*128 + d0], a1 = bh1[k1*128 + d1];
        for (int cc = 0; cc < 256; cc += 16) {
            float wa[16], wb[16];
            #pragma unroll
            for (int u = 0; u < 16; ++u) {
                wa[u] = Wh1[(k0*256 + cc + u)*128 + d0];               // L3-warm
                wb[u] = Wh1[(k1*256 + cc + u)*128 + d1];
            }
            #pragma unroll
            for (int u = 0; u < 16; u += 4) {
                const float4 a4 = *(const float4*)&agg_s[cc + u];
                a0 += a4.x*wa[u] + a4.y*wa[u+1] + a4.z*wa[u+2] + a4.w*wa[u+3];
                a1 += a4.x*wb[u] + a4.y*wb[u+1] + a4.z*wb[u+2] + a4.w*wb[u+3];
            }
        }
        h1h_s[k0][d0] = fmaxf(a0, 0.f);
        h1h_s[k1][d1] = fmaxf(a1, 0.f);
    }
    __syncthreads();

    // final dot: R0-proven strictly-sequential scalar accumulation (bit-exact)
    if (tid < 4) {
        float acc = bh2[tid];
        for (int d = 0; d < 128; ++d) acc += h1h_s[tid][d] * Wh2[tid*128 + d];
        out[tid] = acc;
    }
}

extern "C" void kernel_launch(void* const* d_in, const int* in_sizes, int n_in,
                              void* d_out, int out_size, void* d_ws, size_t ws_size,
                              hipStream_t stream) {
    const float* positions = (const float*)d_in[0];
    const float* grid      = (const float*)d_in[1];
    const float* W1  = (const float*)d_in[2];
    const float* b1  = (const float*)d_in[3];
    const float* W2  = (const float*)d_in[4];
    const float* b2  = (const float*)d_in[5];
    const float* W3  = (const float*)d_in[6];
    const float* b3  = (const float*)d_in[7];
    const float* Wn1 = (const float*)d_in[8];
    const float* bn1 = (const float*)d_in[9];
    const float* Wn2 = (const float*)d_in[10];
    const float* bn2 = (const float*)d_in[11];
    const float* Wh1 = (const float*)d_in[12];
    const float* bh1 = (const float*)d_in[13];
    const float* Wh2 = (const float*)d_in[14];
    const float* bh2 = (const float*)d_in[15];
    float* out = (float*)d_out;

    char* ws = (char*)d_ws;
    float* tpart_ws = (float*)ws;                 // 8*256 f32
    float* warm_ws  = (float*)(ws + 8192);        // 8*256 f32 sink

    hipLaunchKernelGGL(kA_grid, dim3(8), dim3(256), 0, stream,
                       positions, grid, W1, b1, W2, b2, W3, b3,
                       Wn1, bn1, Wn2, Wh1, tpart_ws, warm_ws);
    hipLaunchKernelGGL(kB_head, dim3(1), dim3(256), 0, stream,
                       Wn2, bn2, Wh1, bh1, Wh2, bh2, tpart_ws, out);
}

// Round 4
// 118.248 us; speedup vs baseline: 1.2059x; 1.1430x over previous
//
#include <hip/hip_runtime.h>

// ---------------------------------------------------------------------------
// Output depends ONLY on positions[0:64]. ~25 MFLOP total.
//
// R4: latency-war. R3's kA = 42us @ 0.6% HBM: ~32 serial chunk-wait rounds.
// Fix: 6 micro-kernels; each stages its whole weight slice into LDS with
// global_load_lds(width=16) issued at kernel ENTRY -> ONE vmcnt drain
// (__syncthreads) per kernel. Parallelism (64/16 blocks) replaces chunking.
//
// BIT-EXACTNESS: harness demands bit-exact bf16 (R1 failed by one ulp@mag4).
// Every per-output accumulation below is the VERBATIM expression structure
// from the R2/R3 kernel that scored absmax 0.0. Only the load source (LDS)
// and block/thread ownership changed. Do not reassociate anything.
// ---------------------------------------------------------------------------

__device__ __forceinline__ void async_cp16(const float* g, float* l) {
    __builtin_amdgcn_global_load_lds(
        (const __attribute__((address_space(1))) void*)g,
        (__attribute__((address_space(3))) void*)l, 16, 0, 0);
}

// contiguous: nfloats multiple of 256; 1 inst moves 256 floats (64 lanes x 16B)
__device__ __forceinline__ void stage_contig(const float* g, float* l, int nfloats, int tid) {
    const int lane = tid & 63, wv = tid >> 6;
    const int ninst = nfloats >> 8;
    for (int i = wv; i < ninst; i += 4)
        async_cp16(g + i*256 + lane*4, l + i*256);
}
// 32-column slice of row-major [nrows][ld] starting at col j0 -> LDS [r][32].
// 1 inst moves 8 rows (8 rows x 32 floats = 256 floats).
__device__ __forceinline__ void stage_slice32(const float* g, float* l, int ld, int j0, int nrows, int tid) {
    const int lane = tid & 63, wv = tid >> 6;
    const int r = lane >> 3, c4 = (lane & 7) << 2;
    const int ninst = nrows >> 3;
    for (int i = wv; i < ninst; i += 4)
        async_cp16(g + (i*8 + r)*ld + j0 + c4, l + i*256);
}

// ---- K0 (1 block): winner, h1(64x64), h2g(64x128) -> ws -------------------
__global__ __launch_bounds__(256) void k0_backbone(
    const float* __restrict__ positions, const float* __restrict__ grid,
    const float* __restrict__ W1, const float* __restrict__ b1,
    const float* __restrict__ W2, const float* __restrict__ b2,
    float* __restrict__ h2g_ws, int* __restrict__ win_ws)
{
    __shared__ __align__(16) float w2_s[64*128];     // 32 KB
    __shared__ __align__(16) float h1_s[64][64];     // 16 KB
    __shared__ float pos_s[192], grid_s[192], w1_s[192], b1_s[64];
    __shared__ int idx_s[64], win_s[64];

    const int tid = threadIdx.x;
    stage_contig(W2, w2_s, 64*128, tid);             // async, in flight below

    if (tid < 192) { pos_s[tid] = positions[tid]; grid_s[tid] = grid[tid]; w1_s[tid] = W1[tid]; }
    if (tid >= 192) b1_s[tid - 192] = b1[tid - 192];
    const float bb2 = b2[tid & 127];                 // early plain load
    __syncthreads();                                 // drains W2 too (1 round)

    if (tid < 64) {                                  // verbatim R3 argmin
        const float px = pos_s[tid*3], py = pos_s[tid*3+1], pz = pos_s[tid*3+2];
        float best = 3.4e38f; int bi = 0;
        for (int g = 0; g < 64; ++g) {
            const float dx = px - grid_s[g*3];
            const float dy = py - grid_s[g*3+1];
            const float dz = pz - grid_s[g*3+2];
            const float d2 = dx*dx + dy*dy + dz*dz;
            if (d2 < best) { best = d2; bi = g; }
        }
        idx_s[tid] = bi;
    }
    __syncthreads();
    if (tid < 64) {                                  // verbatim winner rule
        int m = -1;
        for (int i = 0; i < 64; ++i) if (idx_s[i] == tid) m = i;
        win_s[tid] = m;
        win_ws[tid] = m;
    }
    __syncthreads();

    // h1 all 64 slots: verbatim R3 expression (t now spans 64)
    #pragma unroll
    for (int u = 0; u < 16; ++u) {
        const int e = tid + u*256;
        const int t = e >> 6, k = e & 63;
        int r = win_s[t]; if (r < 0) r = 0;
        const float acc = b1_s[k] + pos_s[r*3]*w1_s[k] + pos_s[r*3+1]*w1_s[64+k]
                                  + pos_s[r*3+2]*w1_s[128+k];
        h1_s[t][k] = fmaxf(acc, 0.f);
    }
    __syncthreads();

    // h2g: verbatim R3 h2 stage, looped over the 8 row-groups; w from LDS
    {
        const int d = tid & 127, t0 = tid >> 7;
        for (int bp = 0; bp < 8; ++bp) {
            float acc[4];
            #pragma unroll
            for (int m = 0; m < 4; ++m) acc[m] = bb2;
            for (int kc = 0; kc < 64; kc += 16) {
                float w[16];
                #pragma unroll
                for (int u = 0; u < 16; ++u) w[u] = w2_s[(kc+u)*128 + d];
                #pragma unroll
                for (int u = 0; u < 16; u += 4) {
                    #pragma unroll
                    for (int m = 0; m < 4; ++m) {
                        const float4 h4 = *(const float4*)&h1_s[bp*8 + t0 + 2*m][kc + u];
                        acc[m] += h4.x*w[u] + h4.y*w[u+1] + h4.z*w[u+2] + h4.w*w[u+3];
                    }
                }
            }
            #pragma unroll
            for (int m = 0; m < 4; ++m)
                h2g_ws[(bp*8 + t0 + 2*m)*128 + d] = fmaxf(acc[m], 0.f);
        }
    }
}

// ---- K1 (8 blocks, 32-col W3 slices): gf(64x256) -> ws --------------------
__global__ __launch_bounds__(256) void k1_gf(
    const float* __restrict__ W3, const float* __restrict__ b3,
    const float* __restrict__ h2g_ws, const int* __restrict__ win_ws,
    float* __restrict__ gf_ws)
{
    __shared__ __align__(16) float w3_s[128*32];     // 16 KB slice
    __shared__ __align__(16) float h2_s[64*128];     // 32 KB
    __shared__ int win_s[64];

    const int tid = threadIdx.x;
    const int j0  = blockIdx.x * 32;
    stage_slice32(W3, w3_s, 256, j0, 128, tid);      // async
    stage_contig(h2g_ws, h2_s, 64*128, tid);         // async

    const int jl = tid & 31, g = tid >> 5;
    const int j  = j0 + jl;
    const float bb = b3[j];                          // early plain load
    if (tid < 64) win_s[tid] = win_ws[tid];
    __syncthreads();                                 // ONE drain

    // verbatim R3 gf stage: acc[t] over this thread's 8 rows (group g)
    float acc[8];
    #pragma unroll
    for (int t = 0; t < 8; ++t) acc[t] = 0.f;
    for (int dc = 0; dc < 128; dc += 16) {
        float w[16];
        #pragma unroll
        for (int u = 0; u < 16; ++u) w[u] = w3_s[(dc+u)*32 + jl];
        #pragma unroll
        for (int u = 0; u < 16; u += 4) {
            #pragma unroll
            for (int t = 0; t < 8; ++t) {
                const float4 h4 = *(const float4*)&h2_s[(g*8 + t)*128 + dc + u];
                acc[t] += h4.x*w[u] + h4.y*w[u+1] + h4.z*w[u+2] + h4.w*w[u+3];
            }
        }
    }
    #pragma unroll
    for (int t = 0; t < 8; ++t)
        gf_ws[(g*8 + t)*256 + j] = (win_s[g*8 + t] >= 0) ? (acc[t] + bb) : 0.f;
}

// ---- K2 (64 blocks = 8 row-groups x 8 col-slices): tpart(8x256) -> ws -----
__global__ __launch_bounds__(256) void k2_tpart(
    const float* __restrict__ Wn1, const float* __restrict__ bn1,
    const float* __restrict__ gf_ws, float* __restrict__ tpart_ws)
{
    __shared__ __align__(16) float wn1_s[256*32];    // 32 KB slice
    __shared__ __align__(16) float gf_s[8*256];      // 8 KB (this row-group)
    __shared__ float r_s[256];

    const int tid = threadIdx.x;
    const int bg  = blockIdx.x >> 3;                 // row group 0..7
    const int j0  = (blockIdx.x & 7) * 32;
    stage_slice32(Wn1, wn1_s, 256, j0, 256, tid);    // async
    stage_contig(gf_ws + bg*8*256, gf_s, 8*256, tid);// async

    const int jl = tid & 31, t = tid >> 5;           // one (row t, col jl) each
    const float bb = bn1[j0 + jl];                   // early plain load
    __syncthreads();                                 // ONE drain

    // verbatim R3 Wn1 inner chunk structure, single t per thread
    float acc = bb;
    for (int cc = 0; cc < 256; cc += 32) {
        float w[32];
        #pragma unroll
        for (int u = 0; u < 32; ++u) w[u] = wn1_s[(cc+u)*32 + jl];
        #pragma unroll
        for (int u = 0; u < 32; u += 4) {
            const float4 g4 = *(const float4*)&gf_s[t*256 + cc + u];
            acc += g4.x*w[u] + g4.y*w[u+1] + g4.z*w[u+2] + g4.w*w[u+3];
        }
    }
    r_s[tid] = fmaxf(acc, 0.f);
    __syncthreads();
    if (t == 0) {                                    // ps = ((0+r0)+r1)+... asc, as R3
        float ps = 0.f;
        #pragma unroll
        for (int tt = 0; tt < 8; ++tt) ps += r_s[tt*32 + jl];
        tpart_ws[bg*256 + j0 + jl] = ps;
    }
}

// ---- K3 (8 blocks x 32 cols): tbar -> agg(256) -> ws ----------------------
__global__ __launch_bounds__(256) void k3_agg(
    const float* __restrict__ Wn2, const float* __restrict__ bn2,
    const float* __restrict__ tpart_ws, float* __restrict__ agg_ws)
{
    __shared__ __align__(16) float wn2_s[256*32];    // 32 KB slice
    __shared__ __align__(16) float tp_s[8*256];      // 8 KB
    __shared__ __align__(16) float tbar_s[256];

    const int tid = threadIdx.x;
    const int c0  = blockIdx.x * 32;
    stage_slice32(Wn2, wn2_s, 256, c0, 256, tid);    // async
    stage_contig(tpart_ws, tp_s, 8*256, tid);        // async

    const float bb = (tid < 32) ? bn2[c0 + tid] : 0.f;  // early plain load
    __syncthreads();                                 // ONE drain

    {   // verbatim R3 tbar: q ascending then *1/64
        float tb = 0.f;
        #pragma unroll
        for (int q = 0; q < 8; ++q) tb += tp_s[q*256 + tid];
        tbar_s[tid] = tb * (1.f/64.f);
    }
    __syncthreads();

    if (tid < 32) {                                  // verbatim R3 agg chunks
        float acc = bb;
        for (int jc = 0; jc < 256; jc += 32) {
            float w[32];
            #pragma unroll
            for (int u = 0; u < 32; ++u) w[u] = wn2_s[(jc+u)*32 + tid];
            #pragma unroll
            for (int u = 0; u < 32; u += 4) {
                const float4 t4 = *(const float4*)&tbar_s[jc + u];
                acc += t4.x*w[u] + t4.y*w[u+1] + t4.z*w[u+2] + t4.w*w[u+3];
            }
        }
        agg_ws[c0 + tid] = acc;
    }
}

// ---- K4 (16 blocks = 4 heads x 4 d-quarters): h1h(4x128) -> ws ------------
__global__ __launch_bounds__(256) void k4_heads(
    const float* __restrict__ Wh1, const float* __restrict__ bh1,
    const float* __restrict__ agg_ws, float* __restrict__ h1h_ws)
{
    __shared__ __align__(16) float wh1_s[256*32];    // 32 KB slice
    __shared__ __align__(16) float agg_s[256];

    const int tid = threadIdx.x;
    const int k   = blockIdx.x >> 2;
    const int d0  = (blockIdx.x & 3) * 32;
    stage_slice32(Wh1 + k*256*128, wh1_s, 128, d0, 256, tid);  // async
    stage_contig(agg_ws, agg_s, 256, tid);                     // async

    const float bia = (tid < 32) ? bh1[k*128 + d0 + tid] : 0.f; // early load
    __syncthreads();                                 // ONE drain

    if (tid < 32) {                                  // verbatim R3 head chunks
        float acc = bia;
        for (int cc = 0; cc < 256; cc += 16) {
            float wa[16];
            #pragma unroll
            for (int u = 0; u < 16; ++u) wa[u] = wh1_s[(cc+u)*32 + tid];
            #pragma unroll
            for (int u = 0; u < 16; u += 4) {
                const float4 a4 = *(const float4*)&agg_s[cc + u];
                acc += a4.x*wa[u] + a4.y*wa[u+1] + a4.z*wa[u+2] + a4.w*wa[u+3];
            }
        }
        h1h_ws[k*128 + d0 + tid] = fmaxf(acc, 0.f);
    }
}

// ---- K5 (1 block): final 4 dots -> out ------------------------------------
__global__ __launch_bounds__(256) void k5_out(
    const float* __restrict__ Wh2, const float* __restrict__ bh2,
    const float* __restrict__ h1h_ws, float* __restrict__ out)
{
    __shared__ __align__(16) float h1h_s[512];
    __shared__ __align__(16) float wh2_s[512];
    const int tid = threadIdx.x;
    stage_contig(h1h_ws, h1h_s, 512, tid);           // async
    stage_contig(Wh2,    wh2_s, 512, tid);           // async
    const float bb = (tid < 4) ? bh2[tid] : 0.f;     // early plain load
    __syncthreads();                                 // ONE drain

    if (tid < 4) {                                   // verbatim R3 scalar dot
        float acc = bb;
        for (int d = 0; d < 128; ++d) acc += h1h_s[tid*128 + d] * wh2_s[tid*128 + d];
        out[tid] = acc;
    }
}

extern "C" void kernel_launch(void* const* d_in, const int* in_sizes, int n_in,
                              void* d_out, int out_size, void* d_ws, size_t ws_size,
                              hipStream_t stream) {
    const float* positions = (const float*)d_in[0];
    const float* grid      = (const float*)d_in[1];
    const float* W1  = (const float*)d_in[2];
    const float* b1  = (const float*)d_in[3];
    const float* W2  = (const float*)d_in[4];
    const float* b2  = (const float*)d_in[5];
    const float* W3  = (const float*)d_in[6];
    const float* b3  = (const float*)d_in[7];
    const float* Wn1 = (const float*)d_in[8];
    const float* bn1 = (const float*)d_in[9];
    const float* Wn2 = (const float*)d_in[10];
    const float* bn2 = (const float*)d_in[11];
    const float* Wh1 = (const float*)d_in[12];
    const float* bh1 = (const float*)d_in[13];
    const float* Wh2 = (const float*)d_in[14];
    const float* bh2 = (const float*)d_in[15];
    float* out = (float*)d_out;

    char* ws = (char*)d_ws;                 // every buffer fully rewritten per call
    float* h2g_ws   = (float*)(ws + 0);         // 64*128 f = 32 KB
    int*   win_ws   = (int*)  (ws + 32768);     // 64 i32
    float* gf_ws    = (float*)(ws + 36864);     // 64*256 f = 64 KB
    float* tpart_ws = (float*)(ws + 102400);    // 8*256 f = 8 KB
    float* agg_ws   = (float*)(ws + 110592);    // 256 f
    float* h1h_ws   = (float*)(ws + 111616);    // 512 f

    hipLaunchKernelGGL(k0_backbone, dim3(1),  dim3(256), 0, stream,
                       positions, grid, W1, b1, W2, b2, h2g_ws, win_ws);
    hipLaunchKernelGGL(k1_gf,      dim3(8),  dim3(256), 0, stream,
                       W3, b3, h2g_ws, win_ws, gf_ws);
    hipLaunchKernelGGL(k2_tpart,   dim3(64), dim3(256), 0, stream,
                       Wn1, bn1, gf_ws, tpart_ws);
    hipLaunchKernelGGL(k3_agg,     dim3(8),  dim3(256), 0, stream,
                       Wn2, bn2, tpart_ws, agg_ws);
    hipLaunchKernelGGL(k4_heads,   dim3(16), dim3(256), 0, stream,
                       Wh1, bh1, agg_ws, h1h_ws);
    hipLaunchKernelGGL(k5_out,     dim3(1),  dim3(256), 0, stream,
                       Wh2, bh2, h1h_ws, out);
}